// Round 5
// baseline (286.247 us; speedup 1.0000x reference)
//
#include <hip/hip_runtime.h>

// ---------------------------------------------------------------------------
// QuantumLayer: B=16384 states of 10 qubits (DIM=1024 complex amps).
// One wave (64 lanes) per state; each lane holds 16 complex amps in VGPRs.
// Amp index k (10 bits): lane = k>>4 (storage bits 9..4), reg = k&15 (bits 3..0).
// CNOTs are compile-time GF(2) index relabeling (matrix S); each Rot gate acts
// along direction v = S e_b with side bit parity(R & k), R = row of S^{-1}.
// Cross-lane partner fetches: ds_swizzle (xor<32) / ds_bpermute (xor>=32).
// R5: complex amps as float2 ext-vectors so the backend can emit v_pk_*_f32
// (halves VALU issue + code size); __launch_bounds__(256,8) pins the 64-VGPR
// occupancy step so the allocator stops rematerializing at VGPR=32.
// ---------------------------------------------------------------------------

namespace {

constexpr int NQ = 10;
constexpr int NGATES = 50;   // Rot gates of layers 1..5 (layer 0 fused into init)

struct Sched {
  unsigned v[NGATES];
  unsigned R[NGATES];
  unsigned Rfin[NQ];
  bool ok;
};

constexpr int par(unsigned x) { int p = 0; while (x) { p ^= 1; x &= x - 1; } return p; }

constexpr Sched make_sched() {
  Sched s{};
  unsigned cols[NQ] = {};
  unsigned rows[NQ] = {};
  for (int b = 0; b < NQ; ++b) { cols[b] = 1u << b; rows[b] = 1u << b; }
  int g = 0;
  for (int l = 0; l < 6; ++l) {
    if (l > 0) {
      for (int w = 0; w < NQ; ++w) {
        int b = 9 - w;
        s.v[g] = cols[b];
        s.R[g] = rows[b];
        ++g;
      }
    }
    int r = l % 9 + 1;
    for (int w = 0; w < NQ; ++w) {
      int c = w, t = (w + r) % NQ;
      int cb = 9 - c, tb = 9 - t;
      cols[cb] ^= cols[tb];
      rows[tb] ^= rows[cb];
    }
  }
  for (int b = 0; b < NQ; ++b) s.Rfin[b] = rows[b];
  bool ok = true;
  for (int a = 0; a < NQ; ++a)
    for (int b = 0; b < NQ; ++b)
      if (par(rows[a] & cols[b]) != (a == b ? 1 : 0)) ok = false;
  s.ok = ok;
  return s;
}

constexpr Sched SCH = make_sched();
static_assert(SCH.ok, "GF(2) schedule inconsistent");

} // namespace

typedef float f2 __attribute__((ext_vector_type(2)));

__device__ float g_rots[60 * 8];

__global__ void setup_rots_kernel(const float* __restrict__ wts) {
  int idx = threadIdx.x;
  if (idx < 60) {
    float phi = wts[idx * 3 + 0], th = wts[idx * 3 + 1], om = wts[idx * 3 + 2];
    float c, sn;
    sincosf(0.5f * th, &sn, &c);
    float ca, sa, cb, sb;
    sincosf(0.5f * (phi + om), &sa, &ca);
    sincosf(0.5f * (phi - om), &sb, &cb);
    float* o = g_rots + idx * 8;
    o[0] =  ca * c;   o[1] = -sa * c;
    o[2] = -cb * sn;  o[3] = -sb * sn;
    o[4] =  cb * sn;  o[5] = -sb * sn;
    o[6] =  ca * c;   o[7] =  sa * c;
  }
}

// ---- packed-complex helpers ------------------------------------------------
__device__ __forceinline__ f2 swapneg(f2 v) {   // i * v  ==  (-v.y, v.x)
  f2 r; r.x = -v.y; r.y = v.x; return r;
}
__device__ __forceinline__ f2 cmul(f2 u, f2 v) {  // complex multiply
  return u.x * v + u.y * swapneg(v);
}

// ---- cross-lane primitives -------------------------------------------------
__device__ __forceinline__ float bperm1(int baddr, float v) {
  return __int_as_float(__builtin_amdgcn_ds_bpermute(baddr, __float_as_int(v)));
}

template<int M>
__device__ __forceinline__ float swz1(float v) {
  // BitMode xor swizzle within 32-lane groups: offset = (xor<<10) | and_mask 0x1F
  return __int_as_float(__builtin_amdgcn_ds_swizzle(__float_as_int(v), (M << 10) | 0x1F));
}

typedef unsigned uint2v __attribute__((ext_vector_type(2)));

// full-wave add-reduction: 5 swizzle-xor levels + permlane32_swap half merge
__device__ __forceinline__ float red64(float t) {
  t += swz1<1>(t);  t += swz1<2>(t);  t += swz1<4>(t);
  t += swz1<8>(t);  t += swz1<16>(t);
  uint2v r = __builtin_amdgcn_permlane32_swap(__float_as_uint(t), __float_as_uint(t),
                                              false, false);
  return __uint_as_float(r.x) + __uint_as_float(r.y);
}

// ---- one Rot gate along compile-time direction v, side-row R ---------------
template<int G>
__device__ __forceinline__ void apply_gate(const float4 uA, const float4 uB,
                                           f2 (&a)[16], const int lane) {
  constexpr int v  = (int)SCH.v[G];
  constexpr int R  = (int)SCH.R[G];
  constexpr int vl = v & 15, vh = v >> 4;
  constexpr int Rl = R & 15, Rh = R >> 4;

  bool ph = false;
  if constexpr (Rh != 0) ph = (__popc(lane & Rh) & 1) != 0;
  // class A: parity(i&Rl)==0 -> side==ph ; class B: side==!ph
  // coefficient = diag (d) and off-diag (o) complex scalars per class
  const float dAr = ph ? uB.z : uA.x, dAi = ph ? uB.w : uA.y;
  const float oAr = ph ? uB.x : uA.z, oAi = ph ? uB.y : uA.w;
  const float dBr = ph ? uA.x : uB.z, dBi = ph ? uA.y : uB.w;
  const float oBr = ph ? uA.z : uB.x, oBi = ph ? uA.w : uB.y;

  if constexpr (vh == 0) {
    // in-register pairs (i, i^vl)
#pragma unroll
    for (int i = 0; i < 16; ++i) {
      const int j = i ^ vl;
      if (j > i) {
        const bool ci = (__popc(i & Rl) & 1) != 0;   // compile-time after unroll
        const bool cj = (__popc(j & Rl) & 1) != 0;
        const float d0r = ci ? dBr : dAr, d0i = ci ? dBi : dAi;
        const float o0r = ci ? oBr : oAr, o0i = ci ? oBi : oAi;
        const float d1r = cj ? dBr : dAr, d1i = cj ? dBi : dAi;
        const float o1r = cj ? oBr : oAr, o1i = cj ? oBi : oAi;
        const f2 A = a[i], B = a[j];
        const f2 At = swapneg(A), Bt = swapneg(B);
        a[i] = d0r * A + d0i * At + o0r * B + o0i * Bt;
        a[j] = d1r * B + d1i * Bt + o1r * A + o1i * At;
      }
    }
  } else {
    int baddr = 0;
    if constexpr (vh >= 32) baddr = (lane ^ vh) << 2;  // hoisted per gate
    auto fetch2 = [&](f2 x) -> f2 {
      f2 r;
      if constexpr (vh < 32) { r.x = swz1<vh>(x.x); r.y = swz1<vh>(x.y); }
      else                   { r.x = bperm1(baddr, x.x); r.y = bperm1(baddr, x.y); }
      return r;
    };

    if constexpr (vl == 0) {
      // pure cross-lane: partner (lane^vh, i)
#pragma unroll
      for (int i = 0; i < 16; ++i) {
        const f2 P = fetch2(a[i]);
        const bool ci = (__popc(i & Rl) & 1) != 0;
        const float ddr = ci ? dBr : dAr, ddi = ci ? dBi : dAi;
        const float oor = ci ? oBr : oAr, ooi = ci ? oBi : oAi;
        const f2 A = a[i];
        a[i] = ddr * A + ddi * swapneg(A) + oor * P + ooi * swapneg(P);
      }
    } else {
      // mixed: (lane,i) pairs with (lane^vh, i^vl); fetch before write per pair
#pragma unroll
      for (int i = 0; i < 16; ++i) {
        const int j = i ^ vl;
        if (j > i) {
          const f2 Qj = fetch2(a[j]);
          const f2 Qi = fetch2(a[i]);
          const bool ci = (__popc(i & Rl) & 1) != 0;
          const bool cj = (__popc(j & Rl) & 1) != 0;
          const float d0r = ci ? dBr : dAr, d0i = ci ? dBi : dAi;
          const float o0r = ci ? oBr : oAr, o0i = ci ? oBi : oAi;
          const float d1r = cj ? dBr : dAr, d1i = cj ? dBi : dAi;
          const float o1r = cj ? oBr : oAr, o1i = cj ? oBi : oAi;
          const f2 A = a[i], B = a[j];
          a[i] = d0r * A + d0i * swapneg(A) + o0r * Qj + o0i * swapneg(Qj);
          a[j] = d1r * B + d1i * swapneg(B) + o1r * Qi + o1i * swapneg(Qi);
        }
      }
    }
  }
}

// Distance-1 software pipeline: gate G+1's coefficient loads issue BEFORE
// gate G's FMA block (with 64-VGPR budget the allocator can now keep them).
template<int G>
__device__ __forceinline__ void run_gates(const float4 uA, const float4 uB,
                                          f2 (&a)[16], const int lane) {
  float4 nA, nB;
  if constexpr (G + 1 < NGATES) {
    nA = *(const float4*)(g_rots + (NQ + G + 1) * 8);
    nB = *(const float4*)(g_rots + (NQ + G + 1) * 8 + 4);
  }
  apply_gate<G>(uA, uB, a, lane);
  if constexpr (G + 1 < NGATES) run_gates<G + 1>(nA, nB, a, lane);
}

__launch_bounds__(256, 8)
__global__ void qlayer_kernel(const float* __restrict__ x,
                              const float* __restrict__ W,
                              const float* __restrict__ bias,
                              float* __restrict__ out) {
  const int lane = threadIdx.x & 63;
  const int s = blockIdx.x * 4 + (threadIdx.x >> 6);

  // ---- angles = x @ W^T + b ; RX cos/sin ----------------------------------
  const float xl = x[s * 64 + lane];
  float wl[NQ];
#pragma unroll
  for (int w = 0; w < NQ; ++w) wl[w] = W[w * 64 + lane];

  float cw[NQ], sw[NQ];
#pragma unroll
  for (int w = 0; w < NQ; ++w) {
    const float p = red64(xl * wl[w]);
    const float half = 0.5f * (p + bias[w]);
    float ss, cc;
    __sincosf(half, &ss, &cc);
    sw[w] = ss; cw[w] = cc;
  }

  // ---- fused per-qubit vector g_w = Rot0_w * RX_w * |0> -------------------
  f2 g0[NQ], g1[NQ];
#pragma unroll
  for (int w = 0; w < NQ; ++w) {
    const float4 uA = *(const float4*)(g_rots + w * 8);
    const float4 uB = *(const float4*)(g_rots + w * 8 + 4);
    const float c = cw[w], sn = sw[w];
    g0[w].x = uA.x * c + uA.w * sn;
    g0[w].y = uA.y * c - uA.z * sn;
    g1[w].x = uB.x * c + uB.w * sn;
    g1[w].y = uB.y * c - uB.z * sn;
  }

  // ---- product state ------------------------------------------------------
  f2 F;
  {
    const int b0 = (lane >> 5) & 1;
    F = b0 ? g1[0] : g0[0];
#pragma unroll
    for (int w = 1; w < 6; ++w) {
      const int bt = (lane >> (5 - w)) & 1;
      F = cmul(F, bt ? g1[w] : g0[w]);
    }
  }

  f2 a[16];
  {
    f2 th[4], tl[4];
#pragma unroll
    for (int a2 = 0; a2 < 4; ++a2) {
      const int bh = (a2 >> 1) & 1, bl = a2 & 1;
      th[a2] = cmul(bh ? g1[6] : g0[6], bl ? g1[7] : g0[7]);
      tl[a2] = cmul(bh ? g1[8] : g0[8], bl ? g1[9] : g0[9]);
    }
#pragma unroll
    for (int i = 0; i < 16; ++i)
      a[i] = cmul(F, cmul(th[i >> 2], tl[i & 3]));
  }

  // ---- 50 Rot gates (pipelined coefficient prefetch) ----------------------
  {
    const float4 uA0 = *(const float4*)(g_rots + NQ * 8);
    const float4 uB0 = *(const float4*)(g_rots + NQ * 8 + 4);
    run_gates<0>(uA0, uB0, a, lane);
  }

  // ---- Z expectations via 4-bit Walsh-Hadamard transform ------------------
  float pb[16];
#pragma unroll
  for (int i = 0; i < 16; ++i) pb[i] = a[i].x * a[i].x + a[i].y * a[i].y;
#pragma unroll
  for (int lev = 1; lev < 16; lev <<= 1) {
#pragma unroll
    for (int i = 0; i < 16; ++i) {
      if (!(i & lev)) {
        const float A = pb[i], Bv = pb[i | lev];
        pb[i] = A + Bv;
        pb[i | lev] = A - Bv;
      }
    }
  }
#pragma unroll
  for (int q = 0; q < NQ; ++q) {
    const int R = (int)SCH.Rfin[9 - q];
    const int Rl = R & 15, Rh = R >> 4;
    float t = pb[Rl];
    if (Rh != 0) {
      const bool ph = (__popc(lane & Rh) & 1) != 0;
      t = ph ? -t : t;
    }
    t = red64(t);
    if (lane == 0) out[s * NQ + q] = t;
  }
}

extern "C" void kernel_launch(void* const* d_in, const int* in_sizes, int n_in,
                              void* d_out, int out_size, void* d_ws, size_t ws_size,
                              hipStream_t stream) {
  const float* x   = (const float*)d_in[0];
  const float* W   = (const float*)d_in[1];
  const float* b   = (const float*)d_in[2];
  const float* wts = (const float*)d_in[3];
  float* out = (float*)d_out;
  const int B = in_sizes[0] / 64;

  setup_rots_kernel<<<1, 64, 0, stream>>>(wts);
  qlayer_kernel<<<B / 4, 256, 0, stream>>>(x, W, b, out);
}